// Round 5
// baseline (538.286 us; speedup 1.0000x reference)
//
#include <hip/hip_runtime.h>
#include <math.h>

// I-BERT IntSoftmax, exact-numerics replication of the JAX reference.
// x: (1,12,2048,2048) f32; 24576 rows of S=2048.
// R5: single persistent kernel (512 blocks, all co-resident), hand-rolled
//     device-scope barrier; wave-per-row phase 2 with zero block barriers.

#define ROW_S 2048
#define GRID  512
#define TPB   256

typedef float floatx4 __attribute__((ext_vector_type(4)));

struct Gsync {
    unsigned count;      // arrive counter
    unsigned flag;       // scalars-ready flag
    unsigned amax_bits;  // global max|x| as monotone uint bits (amax >= 0)
    unsigned _pad;
    double exp_sf_d;     // exp_sf (f64) — fixedpoint_mul divisor
    double inv_exp_sf;   // RN(1/exp_sf_d)
    double m_int;        // 31-bit mantissa
    double inv_pow;      // 2^(e-31) exact
    float  sf, inv_sf, x0_int, inv_x0, b_int, c_int, thirty_x0, _pad2;
};

// Markstein: with inv = RN(1/b), returns RN(a/b) bit-exactly.
__device__ __forceinline__ float div_rn(float a, float b, float inv) {
    const float q0 = __fmul_rn(a, inv);
    const float r  = __fmaf_rn(-b, q0, a);
    return __fmaf_rn(r, inv, q0);
}
__device__ __forceinline__ double ddiv_rn(double a, double b, double inv) {
    const double q0 = __dmul_rn(a, inv);
    const double r  = __fma_rn(-b, q0, a);
    return __fma_rn(r, inv, q0);
}

__global__ __launch_bounds__(TPB, 2) void k_fused(const float* __restrict__ x,
                                                  float* __restrict__ out,
                                                  Gsync* __restrict__ g,
                                                  int rows) {
    const int tid  = threadIdx.x;
    const int wave = tid >> 6, lane = tid & 63;
    const int rpb   = rows / GRID;     // 48
    const int iters = rpb >> 2;        // 12 row-groups of 4 (one per wave)
    const int row0  = blockIdx.x * rpb;

    __shared__ float rowmax_s[64];
    __shared__ float amax_s[4];

    const float4* x4 = (const float4*)x;

    // ---------------- phase 1: per-row max + global min/max ----------------
    float vminall = INFINITY, rmall = -INFINITY;
    for (int k = 0; k < iters; ++k) {
        const int rl = (k << 2) + wave;
        const size_t b4 = (size_t)(row0 + rl) * (ROW_S / 4) + lane;
        float4 v[8];
#pragma unroll
        for (int j = 0; j < 8; ++j) v[j] = x4[b4 + 64 * j];
        float vmax = -INFINITY;
#pragma unroll
        for (int j = 0; j < 8; ++j) {
            vmax    = fmaxf(vmax,    fmaxf(fmaxf(v[j].x, v[j].y), fmaxf(v[j].z, v[j].w)));
            vminall = fminf(vminall, fminf(fminf(v[j].x, v[j].y), fminf(v[j].z, v[j].w)));
        }
#pragma unroll
        for (int m = 32; m > 0; m >>= 1) vmax = fmaxf(vmax, __shfl_xor(vmax, m));
        if (lane == 0) rowmax_s[rl] = vmax;   // all lanes hold vmax post-butterfly
        rmall = fmaxf(rmall, vmax);
    }
#pragma unroll
    for (int m = 32; m > 0; m >>= 1) vminall = fminf(vminall, __shfl_xor(vminall, m));
    const float am = fmaxf(-vminall, rmall);  // == max(|min|,|max|) over my rows
    if (lane == 0) amax_s[wave] = am;
    __syncthreads();

    // ---------------- global barrier + scalar computation ----------------
    if (tid == 0) {
        const float amax = fmaxf(fmaxf(amax_s[0], amax_s[1]), fmaxf(amax_s[2], amax_s[3]));
        atomicMax(&g->amax_bits, __float_as_uint(amax));
        __threadfence();
        atomicAdd(&g->count, 1u);
        if (blockIdx.x == 0) {
            while (__hip_atomic_load(&g->count, __ATOMIC_ACQUIRE, __HIP_MEMORY_SCOPE_AGENT) < GRID) {}
            const float sabs = __uint_as_float(
                __hip_atomic_load(&g->amax_bits, __ATOMIC_ACQUIRE, __HIP_MEMORY_SCOPE_AGENT));
            // sym_scale: max(|min|,|max|) == sabs; all f32 RN like the reference
            const float sf    = __fdiv_rn(fmaxf(sabs, 1e-8f), 32767.0f);
            const float x0i   = floorf(__fdiv_rn((float)(-0.6931), sf));
            const float sfsq  = __fmul_rn(sf, sf);
            const float b_int = floorf(__fdiv_rn((float)(0.96963238 / 0.35815147), sf));
            const float c_int = floorf(__fdiv_rn((float)(1.0 / 0.35815147), sfsq));
            const float exp_sf = __fdiv_rn(__fmul_rn((float)(0.35815147), sfsq), 1073741824.0f);
            // global exp_int max is exactly c_int*2^30 (row-max elem: r=0,q=0)
            const float emax   = __fmul_rn(c_int, 1073741824.0f);
            const float act_sf = __fdiv_rn(fmaxf(emax, 1e-8f), 32767.0f);
            const float  nsf = __fdiv_rn(exp_sf, act_sf);
            const double ns  = (double)nsf;
            int E;
            (void)frexp(ns, &E);             // e = floor(log2(ns)) + 1 == E exactly
            g->exp_sf_d   = (double)exp_sf;
            g->inv_exp_sf = 1.0 / (double)exp_sf;
            g->m_int      = rint(ldexp(ns, 31 - E));
            g->inv_pow    = ldexp(1.0, E - 31);
            g->sf         = sf;
            g->inv_sf     = __fdiv_rn(1.0f, sf);
            g->x0_int     = x0i;
            g->inv_x0     = __fdiv_rn(1.0f, x0i);
            g->b_int      = b_int;
            g->c_int      = c_int;
            g->thirty_x0  = __fmul_rn(30.0f, x0i);
            __threadfence();
            __hip_atomic_store(&g->flag, 1u, __ATOMIC_RELEASE, __HIP_MEMORY_SCOPE_AGENT);
        }
    }
    // every thread acquires the flag itself -> its own visibility of scalars
    while (__hip_atomic_load(&g->flag, __ATOMIC_ACQUIRE, __HIP_MEMORY_SCOPE_AGENT) == 0u) {}
    __syncthreads();

    const float  sf     = g->sf,      inv_sf = g->inv_sf;
    const float  x0i    = g->x0_int,  inv_x0 = g->inv_x0;
    const float  b_int  = g->b_int,   c_int  = g->c_int, t30 = g->thirty_x0;
    const double esf    = g->exp_sf_d, iesf  = g->inv_exp_sf;
    const double mi     = g->m_int,    ipow  = g->inv_pow;
    (void)c_int;

    // ---------------- phase 2: wave-per-row, no block barriers ----------------
    floatx4* o4 = (floatx4*)out;
    for (int k = iters - 1; k >= 0; --k) {   // reverse: L2-MRU rows first
        const int rl = (k << 2) + wave;
        const size_t b4 = (size_t)(row0 + rl) * (ROW_S / 4) + lane;
        const float rm = rowmax_s[rl];
        // ximax = xi(row max of x): every x->xi step is monotone non-decreasing,
        // so this equals max over the row of xi bit-exactly.
        float ximax;
        {
            float t = rintf(div_rn(rm, sf, inv_sf));
            t = fminf(fmaxf(t, -32768.0f), 32767.0f);
            t = __fmul_rn(t, sf);
            ximax = div_rn(t, sf, inv_sf);
        }
        float4 v[8];
#pragma unroll
        for (int j = 0; j < 8; ++j) v[j] = x4[b4 + 64 * j];
        float e16[32];
        float ssum = 0.0f;
#pragma unroll
        for (int j = 0; j < 8; ++j) {
            const float xv[4] = {v[j].x, v[j].y, v[j].z, v[j].w};
#pragma unroll
            for (int c = 0; c < 4; ++c) {
                // QuantAct(16): clip(rint(x/sf)); dequant-requant (all RN, no FMA)
                float t = rintf(div_rn(xv[c], sf, inv_sf));
                t = fminf(fmaxf(t, -32768.0f), 32767.0f);
                t = __fmul_rn(t, sf);
                t = div_rn(t, sf, inv_sf);
                // int_exp
                const float xs = __fsub_rn(t, ximax);
                const float xm = fmaxf(xs, t30);
                const float qf = floorf(div_rn(xm, x0i, inv_x0));
                const float r  = __fsub_rn(xm, __fmul_rn(x0i, qf));
                // z = r*(r+b)+c — must NOT contract to FMA
                const float z  = __fadd_rn(__fmul_rn(r, __fadd_rn(r, b_int)), c_int);
                const int   qi = (int)qf;                          // in [0,30]
                const float p2 = __int_as_float((157 - qi) << 23); // exact 2^(30-qi)
                const float ei = fmaxf(floorf(__fmul_rn(z, p2)), 0.0f);
                // fixedpoint_mul in f64 (reference runs in double)
                const double zi = rint(ddiv_rn((double)ei, esf, iesf));
                double ov = rint(__dmul_rn(__dmul_rn(zi, mi), ipow));
                ov = fmin(fmax(ov, -32768.0), 32767.0);
                const float w = (float)ov;    // integer-valued, exact
                e16[4 * j + c] = w;
                ssum += w;    // non-neg ints, row sum < 2^24 -> order-free exact
            }
        }
#pragma unroll
        for (int m = 32; m > 0; m >>= 1) ssum += __shfl_xor(ssum, m);
        const float factor = floorf(__fdiv_rn(4294967296.0f, ssum));
#pragma unroll
        for (int j = 0; j < 8; ++j) {
            floatx4 w;
#pragma unroll
            for (int c = 0; c < 4; ++c) {
                // /2^24 == *2^-24 exact, then *2^-8 exact
                const float oi = floorf(__fmul_rn(__fmul_rn(e16[4 * j + c], factor),
                                                  5.9604644775390625e-8f));
                w[c] = __fmul_rn(oi, 0.00390625f);
            }
            __builtin_nontemporal_store(w, &o4[b4 + 64 * j]);
        }
    }
}

extern "C" void kernel_launch(void* const* d_in, const int* in_sizes, int n_in,
                              void* d_out, int out_size, void* d_ws, size_t ws_size,
                              hipStream_t stream) {
    const float* x = (const float*)d_in[0];
    float* out = (float*)d_out;
    const int n = in_sizes[0];          // 50331648
    const int rows = n / ROW_S;         // 24576

    Gsync* g = (Gsync*)d_ws;
    hipMemsetAsync(d_ws, 0, 64, stream);          // zero count/flag/amax_bits
    k_fused<<<GRID, TPB, 0, stream>>>(x, out, g, rows);
}